// Round 7
// baseline (608.438 us; speedup 1.0000x reference)
//
#include <hip/hip_runtime.h>
#include <hip/hip_bf16.h>

typedef __attribute__((ext_vector_type(8))) short short8;
typedef __attribute__((ext_vector_type(4))) float f32x4;

#define GLOAD_LDS16(gp, lp)                                                      \
  __builtin_amdgcn_global_load_lds(                                              \
      (const __attribute__((address_space(1))) void*)(gp),                       \
      (__attribute__((address_space(3))) void*)(lp), 16, 0, 0)

#define SBAR() asm volatile("s_barrier" ::: "memory")
#define VMC(n)                                                                   \
  do {                                                                           \
    asm volatile("s_waitcnt vmcnt(" #n ")" ::: "memory");                        \
    __builtin_amdgcn_sched_barrier(0);                                           \
  } while (0)

__device__ __forceinline__ unsigned short f2bf_rne(float f) {
  union { float f; unsigned int u; } v; v.f = f;
  unsigned int u = v.u;
  u += 0x7fffu + ((u >> 16) & 1u);
  return (unsigned short)(u >> 16);
}

// ---------------------------------------------------------------- convert ----
__global__ void cvt_f32_bf16(const float* __restrict__ src,
                             unsigned short* __restrict__ dst, int n8) {
  int i = blockIdx.x * blockDim.x + threadIdx.x;
  int stride = gridDim.x * blockDim.x;
  const f32x4* s4 = (const f32x4*)src;
  short8* d8 = (short8*)dst;
  for (; i < n8; i += stride) {
    f32x4 a = s4[2 * i], b = s4[2 * i + 1];
    short8 o;
    o[0] = (short)f2bf_rne(a[0]); o[1] = (short)f2bf_rne(a[1]);
    o[2] = (short)f2bf_rne(a[2]); o[3] = (short)f2bf_rne(a[3]);
    o[4] = (short)f2bf_rne(b[0]); o[5] = (short)f2bf_rne(b[1]);
    o[6] = (short)f2bf_rne(b[2]); o[7] = (short)f2bf_rne(b[3]);
    d8[i] = o;
  }
}

// ------------------------------------------------- T = mask * 2 * (x @ A^T) ---
__global__ __launch_bounds__(256) void lora_t_kernel(
    const unsigned short* __restrict__ xb,
    const unsigned short* __restrict__ Ab,
    const int* __restrict__ offs,
    unsigned short* __restrict__ T)
{
  __shared__ unsigned short xs[64 * 64];
  __shared__ unsigned short as_[32 * 64];
  const int t = threadIdx.x;
  const int m0 = blockIdx.x * 64;
  const int l = t & 63, w = t >> 6;
  const int lr = l & 15, lk = (l >> 4) * 8;
  const int arow = t >> 3, acol = (t & 7) * 8;
  f32x4 acc0 = {0, 0, 0, 0}, acc1 = {0, 0, 0, 0};
  for (int kt = 0; kt < 64; ++kt) {
    __syncthreads();
    const int kof = kt * 64 + acol;
    GLOAD_LDS16(xb + (size_t)(m0 + arow) * 4096 + kof,      (char*)xs + (arow * 64 + acol) * 2);
    GLOAD_LDS16(xb + (size_t)(m0 + 32 + arow) * 4096 + kof, (char*)xs + ((32 + arow) * 64 + acol) * 2);
    GLOAD_LDS16(Ab + (size_t)arow * 4096 + kof,             (char*)as_ + (arow * 64 + acol) * 2);
    __syncthreads();
#pragma unroll
    for (int kk = 0; kk < 2; ++kk) {
      short8 a  = *(const short8*)&xs[(w * 16 + lr) * 64 + kk * 32 + lk];
      short8 b0 = *(const short8*)&as_[lr * 64 + kk * 32 + lk];
      short8 b1 = *(const short8*)&as_[(16 + lr) * 64 + kk * 32 + lk];
      acc0 = __builtin_amdgcn_mfma_f32_16x16x32_bf16(a, b0, acc0, 0, 0, 0);
      acc1 = __builtin_amdgcn_mfma_f32_16x16x32_bf16(a, b1, acc1, 0, 0, 0);
    }
  }
  const int rowb = (l >> 4) * 4;
#pragma unroll
  for (int j = 0; j < 4; ++j) {
    int m = m0 + w * 16 + rowb + j;
    int bb = m >> 12, s = m & 4095;
    int kcut = offs[bb]; if (kcut > 4096) kcut = 4096;
    bool keep = s >= 4096 - kcut;
    T[(size_t)m * 32 + lr]      = keep ? f2bf_rne(2.0f * acc0[j]) : (unsigned short)0;
    T[(size_t)m * 32 + 16 + lr] = keep ? f2bf_rne(2.0f * acc1[j]) : (unsigned short)0;
  }
}

// ------------------------------------------------------------- main GEMM -----
// Same geometry/swizzle/staging as round 6 (256x256, BK=64, 2 slots, 8 waves,
// quarter-wave swizzle chunk^=(row&7), zero bank conflicts verified).
// NEW: depth-1 LDS-read prefetch -- each phase issues the NEXT phase's
// ds_reads before its own MFMA cluster, so the LDS pipe overlaps the MFMA
// pipe instead of serializing (counted lgkmcnt left to the compiler).
// Prefetch never crosses a slot boundary; boundary VMC tightened to 2.
__global__ __launch_bounds__(512, 2) void gemm_kernel(
    const unsigned short* __restrict__ xb,   // [16384][4096] bf16
    const unsigned short* __restrict__ Wb,   // [4096][4096]  bf16
    const unsigned short* __restrict__ Tm,   // [16384][32]   bf16 (mask+scale)
    const unsigned short* __restrict__ Bwb,  // [4096][32]    bf16
    const float* __restrict__ bias,          // [4096]
    float* __restrict__ out)                 // [16384][4096] f32
{
  constexpr int K = 4096;
  extern __shared__ char smem[];             // 128 KiB

  const int bid = blockIdx.x;
  const int swz = (bid & 7) * 128 + (bid >> 3);
  const int m0 = (swz >> 4) * 256;
  const int n0 = (swz & 15) * 256;

  const int t = threadIdx.x;
  const int l = t & 63, w = t >> 6;
  const int wqr = w >> 2;
  const int pr = (w >> 1) & 1;
  const int pc = w & 1;
  const int lr = l & 15, hi = l >> 4;
  const int e0 = (hi ^ (lr & 7)) * 8;        // verified zero-conflict swizzle

  const int srow = t >> 3;
  const int schunk = ((t & 7) ^ ((t >> 3) & 7)) * 8;
  const unsigned short* pA0 = xb + (size_t)(m0 + srow) * K + schunk;
  const unsigned short* pA1 = xb + (size_t)(m0 + 128 + srow) * K + schunk;
  const unsigned short* pB0 = Wb + (size_t)(n0 + srow) * K + schunk;
  const unsigned short* pB1 = Wb + (size_t)(n0 + 128 + srow) * K + schunk;
  unsigned short* sm = (unsigned short*)smem;
  const int ldst = t * 16;

#define STG(PTR, SLOT, ISB, HALF, KT)                                           \
  do {                                                                          \
    const unsigned short* g_ = (PTR) + (KT) * 64;                               \
    char* d_ = smem + (SLOT) * 65536 + (ISB) * 32768 + (HALF) * 16384 + ldst;   \
    GLOAD_LDS16(g_, d_);                                                        \
    GLOAD_LDS16(g_ + (size_t)64 * K, d_ + 8192);                                \
  } while (0)

  f32x4 acc[2][4][4];
  short8 a0f[4], a1f[4], b0f[4], b1f[4];

#define RD_A(DST, AH, KK)                                                       \
  _Pragma("unroll")                                                             \
  for (int i_ = 0; i_ < 4; ++i_)                                                \
    DST[i_] = *(const short8*)((AH) + (pr * 64 + i_ * 16 + lr) * 64 + (e0 ^ ((KK) * 32)));

#define RD_B(DST, BH, KK)                                                       \
  _Pragma("unroll")                                                             \
  for (int j_ = 0; j_ < 4; ++j_)                                                \
    DST[j_] = *(const short8*)((BH) + (pc * 64 + j_ * 16 + lr) * 64 + (e0 ^ ((KK) * 32)));

#define MFMA16(QC, AF, BF)                                                      \
  _Pragma("unroll")                                                             \
  for (int i_ = 0; i_ < 4; ++i_)                                                \
    _Pragma("unroll")                                                           \
    for (int j_ = 0; j_ < 4; ++j_)                                              \
      acc[QC][i_][j_] = __builtin_amdgcn_mfma_f32_16x16x32_bf16(                \
          (AF)[i_], (BF)[j_], acc[QC][i_][j_], 0, 0, 0);

  // --- LoRA prestep: register-direct (L2-resident), initializes acc ---
  {
    const unsigned short* tp = Tm + (size_t)(m0 + wqr * 128 + pr * 64 + lr) * 32 + hi * 8;
    short8 la[4];
#pragma unroll
    for (int i = 0; i < 4; ++i) la[i] = *(const short8*)(tp + i * 512);
    short8 lb[2][4];
#pragma unroll
    for (int qc = 0; qc < 2; ++qc)
#pragma unroll
      for (int j = 0; j < 4; ++j)
        lb[qc][j] = *(const short8*)(Bwb + (size_t)(n0 + qc * 128 + pc * 64 + j * 16 + lr) * 32 + hi * 8);
#pragma unroll
    for (int qc = 0; qc < 2; ++qc)
#pragma unroll
      for (int i = 0; i < 4; ++i)
#pragma unroll
        for (int j = 0; j < 4; ++j)
          acc[qc][i][j] = __builtin_amdgcn_mfma_f32_16x16x32_bf16(
              la[i], lb[qc][j], (f32x4){0.f, 0.f, 0.f, 0.f}, 0, 0, 0);
  }

  // prologue: s0 all 4 halves @kt0, s1.B0 @kt1
  STG(pA0, 0, 0, 0, 0);
  STG(pA1, 0, 0, 1, 0);
  STG(pB0, 0, 1, 0, 0);
  STG(pB1, 0, 1, 1, 0);
  STG(pB0, 1, 1, 0, 1);
  VMC(2);
  SBAR();

  // 4-phase window on slot S (2 kk x 2 qc), depth-1 read prefetch.
  // Phase p issues phase p+1's ds_reads BEFORE p's MFMA; boundary phase
  // reads its own frags in the post-barrier region.  All barriers kept.
#define WINDOW(SLOT, S0, S1, S2, S3, W0, W1, W2, W3)                            \
  {                                                                             \
    const unsigned short* Ah  = sm + (SLOT) * 32768 + wqr * 8192;               \
    const unsigned short* B0h = sm + (SLOT) * 32768 + 16384;                    \
    const unsigned short* B1h = sm + (SLOT) * 32768 + 16384 + 8192;             \
    RD_A(a0f, Ah, 0); RD_B(b0f, B0h, 0);          /* boundary: P0 frags */      \
    /* P0: (qc0,kk0) */                                                         \
    RD_B(b1f, B1h, 0);                                                          \
    S0; SBAR();                                                                 \
    __builtin_amdgcn_s_setprio(1); MFMA16(0, a0f, b0f);                         \
    __builtin_amdgcn_s_setprio(0); W0; SBAR();                                  \
    /* P1: (qc1,kk0) */                                                         \
    RD_A(a1f, Ah, 1); RD_B(b0f, B0h, 1);                                        \
    S1; SBAR();                                                                 \
    __builtin_amdgcn_s_setprio(1); MFMA16(1, a0f, b1f);                         \
    __builtin_amdgcn_s_setprio(0); W1; SBAR();                                  \
    /* P2: (qc0,kk1) */                                                         \
    RD_B(b1f, B1h, 1);                                                          \
    S2; SBAR();                                                                 \
    __builtin_amdgcn_s_setprio(1); MFMA16(0, a1f, b0f);                         \
    __builtin_amdgcn_s_setprio(0); W2; SBAR();                                  \
    /* P3: (qc1,kk1) */                                                         \
    S3; SBAR();                                                                 \
    __builtin_amdgcn_s_setprio(1); MFMA16(1, a1f, b1f);                         \
    __builtin_amdgcn_s_setprio(0); W3; SBAR();                                  \
  }

  // Residency: boundary VMC(2) forces all current-window stages except the
  // last to land (next window reads A0,A1,B1 staged this window + ancient B0).
  // WAR: stages into the in-use slot (S3) are >=2 barrier-pairs after that
  // half's last read issue.  Mid-window VMC(4) waits 2-phase-old loads only.
  for (int I = 0; I < 31; ++I) {
    const int a = 2 * I;
    WINDOW(0, STG(pA0, 1, 0, 0, a + 1), STG(pA1, 1, 0, 1, a + 1),
              STG(pB1, 1, 1, 1, a + 1), STG(pB0, 0, 1, 0, a + 2),
              VMC(4), VMC(4), VMC(4), VMC(2));
    WINDOW(1, STG(pA0, 0, 0, 0, a + 2), STG(pA1, 0, 0, 1, a + 2),
              STG(pB1, 0, 1, 1, a + 2), STG(pB0, 1, 1, 0, a + 3),
              VMC(4), VMC(4), VMC(4), VMC(2));
  }
  // tail: kt 62 (slot0) stages slot1@63 then drains; kt 63 (slot1) bare.
  WINDOW(0, STG(pA0, 1, 0, 0, 63), STG(pA1, 1, 0, 1, 63),
            STG(pB1, 1, 1, 1, 63), ((void)0),
            VMC(4), VMC(4), VMC(2), VMC(0));
  WINDOW(1, ((void)0), ((void)0), ((void)0), ((void)0),
            ((void)0), ((void)0), ((void)0), ((void)0));
#undef WINDOW
#undef MFMA16
#undef RD_A
#undef RD_B
#undef STG

  // epilogue: bias + store (C/D map: col=lr -> N, row=hi*4+e -> M)
  float bv[2][4];
#pragma unroll
  for (int qc = 0; qc < 2; ++qc)
#pragma unroll
    for (int j = 0; j < 4; ++j)
      bv[qc][j] = bias[n0 + qc * 128 + pc * 64 + j * 16 + lr];
  const int rowb = hi * 4;
#pragma unroll
  for (int qc = 0; qc < 2; ++qc)
#pragma unroll
    for (int i = 0; i < 4; ++i)
#pragma unroll
      for (int e = 0; e < 4; ++e) {
        int row = m0 + wqr * 128 + pr * 64 + i * 16 + rowb + e;
        float* orow = out + (size_t)row * 4096 + n0 + qc * 128 + pc * 64;
#pragma unroll
        for (int j = 0; j < 4; ++j) orow[j * 16 + lr] = acc[qc][i][j][e] + bv[qc][j];
      }
}

// ----------------------------------------------------------------- launch ----
extern "C" void kernel_launch(void* const* d_in, const int* in_sizes, int n_in,
                              void* d_out, int out_size, void* d_ws, size_t ws_size,
                              hipStream_t stream) {
  const float* x   = (const float*)d_in[0];
  const int* offs  = (const int*)d_in[1];
  const float* W   = (const float*)d_in[2];
  const float* b   = (const float*)d_in[3];
  const float* A   = (const float*)d_in[4];
  const float* Bw  = (const float*)d_in[5];
  float* out = (float*)d_out;

  char* ws = (char*)d_ws;
  unsigned short* xb  = (unsigned short*)ws;
  unsigned short* Wb  = (unsigned short*)(ws + 134217728);
  unsigned short* Ab  = (unsigned short*)(ws + 167772160);
  unsigned short* Bwb = (unsigned short*)(ws + 168034304);
  unsigned short* T   = (unsigned short*)(ws + 168296448);

  hipFuncSetAttribute((const void*)gemm_kernel,
                      hipFuncAttributeMaxDynamicSharedMemorySize, 131072);

  cvt_f32_bf16<<<2048, 256, 0, stream>>>(x, xb, 67108864 / 8);
  cvt_f32_bf16<<<2048, 256, 0, stream>>>(W, Wb, 16777216 / 8);
  cvt_f32_bf16<<<64, 256, 0, stream>>>(A, Ab, 131072 / 8);
  cvt_f32_bf16<<<64, 256, 0, stream>>>(Bw, Bwb, 131072 / 8);
  lora_t_kernel<<<256, 256, 0, stream>>>(xb, Ab, offs, T);
  gemm_kernel<<<1024, 512, 131072, stream>>>(xb, Wb, T, Bwb, b, out);
}